// Round 1
// 992.317 us; speedup vs baseline: 1.0079x; 1.0079x over previous
//
#include <hip/hip_runtime.h>

// Problem: B=16, K=64, L=M=128, D=768, fp32 in, fp32 out (B*K=1024 scalars).
// out[bk] = sum_l max_m <ctx[bk,l,:], ent[bk,m,:]>
//
// One workgroup per bk; 1024 blocks of 512 threads (8 waves).
// D staged in 12 chunks of 64 (fp32 -> bf16), DOUBLE-BUFFERED in LDS.
// Pipeline per chunk: issue next chunk's global loads (8x float4/thread,
// all in flight, no intermediate vmcnt drains) -> MFMA on current buffer
// -> convert+write next buffer -> single barrier. HBM stays busy across
// the MFMA phase (T14 async-stage split).
//
// LDS: 2 bufs x (ctx+ent) x 128 x 72 bf16 = 73,728 B -> 2 blocks/CU,
// 16 waves/CU. Per-wave acc = 8 x f32x4 = 32 VGPRs (wave owns 16 L-rows).

typedef __attribute__((ext_vector_type(8))) __bf16 bf16x8;
typedef __attribute__((ext_vector_type(4))) __bf16 bf16x4;
typedef __attribute__((ext_vector_type(4))) float f32x4;

#define L_DIM 128
#define D_DIM 768
#define DC    64          // D-chunk
#define NCHUNK (D_DIM / DC)
#define LDP   72          // padded LDS row (bf16 elems): 144 B rows, 16B-aligned frags

__global__ __launch_bounds__(512, 4)
void som_kernel(const float* __restrict__ context, float* __restrict__ out) {
    const int bk   = blockIdx.x;
    const int t    = threadIdx.x;
    const int lane = t & 63;
    const int wave = t >> 6;            // 0..7, owns rows [wave*16, wave*16+16)
    const int quad = (lane >> 4) & 3;   // 0..3
    const int l15  = lane & 15;

    const float* ctx_g = context + (size_t)bk * (2 * L_DIM * D_DIM);
    const float* ent_g = ctx_g + (size_t)(L_DIM * D_DIM);

    __shared__ __bf16 ctx_s[2][L_DIM * LDP];
    __shared__ __bf16 ent_s[2][L_DIM * LDP];
    __shared__ float wave_sum[8];

    // ---- staging geometry: 2048 float4 per array per chunk, 512 threads x 4 ----
    // i-th piece: g = t + i*512 -> row = (t>>4) + i*32, c4 = t & 15
    const int row0 = t >> 4;            // 0..31
    const int c4   = t & 15;
    const float* gc = ctx_g + row0 * D_DIM + c4 * 4;
    const float* ge = ent_g + row0 * D_DIM + c4 * 4;
    const int lds0 = row0 * LDP + c4 * 4;

    f32x4 acc[8];
    const f32x4 zero = {0.f, 0.f, 0.f, 0.f};
#pragma unroll
    for (int ct = 0; ct < 8; ++ct) acc[ct] = zero;

    float4 pc[4], pe[4];

    // ---- prologue: stage chunk 0 into buffer 0 ----
#pragma unroll
    for (int i = 0; i < 4; ++i) {
        pc[i] = *(const float4*)(gc + i * 32 * D_DIM);
        pe[i] = *(const float4*)(ge + i * 32 * D_DIM);
    }
#pragma unroll
    for (int i = 0; i < 4; ++i) {
        bf16x4 qc = {(__bf16)pc[i].x, (__bf16)pc[i].y, (__bf16)pc[i].z, (__bf16)pc[i].w};
        bf16x4 qe = {(__bf16)pe[i].x, (__bf16)pe[i].y, (__bf16)pe[i].z, (__bf16)pe[i].w};
        *(bf16x4*)&ctx_s[0][lds0 + i * 32 * LDP] = qc;
        *(bf16x4*)&ent_s[0][lds0 + i * 32 * LDP] = qe;
    }
    __syncthreads();

    // ---- main loop: one barrier per chunk, loads always in flight ----
    for (int c = 0; c < NCHUNK; ++c) {
        const int cur = c & 1;

        // 1) issue ALL next-chunk loads (8 KB/wave in flight across MFMA)
        if (c < NCHUNK - 1) {
            const int base = (c + 1) * DC;
#pragma unroll
            for (int i = 0; i < 4; ++i) {
                pc[i] = *(const float4*)(gc + i * 32 * D_DIM + base);
                pe[i] = *(const float4*)(ge + i * 32 * D_DIM + base);
            }
        }

        // 2) MFMA on current buffer: wave's 16 rows x all 128 cols
        {
            const __bf16* cs = ctx_s[cur];
            const __bf16* es = ent_s[cur];
#pragma unroll
            for (int ks = 0; ks < 2; ++ks) {
                // A frag: A[m = l15][k = quad*8 + j]
                const bf16x8 a = *(const bf16x8*)&cs[(wave * 16 + l15) * LDP + ks * 32 + quad * 8];
#pragma unroll
                for (int ct = 0; ct < 8; ++ct) {
                    // B frag: B[n = l15][k = quad*8 + j]  (C = A * B^T: same layout as A)
                    const bf16x8 b = *(const bf16x8*)&es[(ct * 16 + l15) * LDP + ks * 32 + quad * 8];
                    acc[ct] = __builtin_amdgcn_mfma_f32_16x16x32_bf16(a, b, acc[ct], 0, 0, 0);
                }
            }
        }

        // 3) convert + write next chunk into the idle buffer
        if (c < NCHUNK - 1) {
            const int nxt = cur ^ 1;
#pragma unroll
            for (int i = 0; i < 4; ++i) {
                bf16x4 qc = {(__bf16)pc[i].x, (__bf16)pc[i].y, (__bf16)pc[i].z, (__bf16)pc[i].w};
                bf16x4 qe = {(__bf16)pe[i].x, (__bf16)pe[i].y, (__bf16)pe[i].z, (__bf16)pe[i].w};
                *(bf16x4*)&ctx_s[nxt][lds0 + i * 32 * LDP] = qc;
                *(bf16x4*)&ent_s[nxt][lds0 + i * 32 * LDP] = qe;
            }
        }
        __syncthreads();
    }

    // ---- epilogue: row-max over 128 cols, then sum of maxes ----
    // C/D layout: col = ct*16 + l15, row = wave*16 + quad*4 + reg.
    float total = 0.f;
#pragma unroll
    for (int reg = 0; reg < 4; ++reg) {
        float m = acc[0][reg];
#pragma unroll
        for (int ct = 1; ct < 8; ++ct) m = fmaxf(m, acc[ct][reg]);
        // max across the 16 lanes of this quad (cols of each 16-wide tile)
        m = fmaxf(m, __shfl_xor(m, 1, 64));
        m = fmaxf(m, __shfl_xor(m, 2, 64));
        m = fmaxf(m, __shfl_xor(m, 4, 64));
        m = fmaxf(m, __shfl_xor(m, 8, 64));
        total += m;   // every lane of the quad holds this row's max
    }
    // per-lane total = sum of this quad's 4 rows; combine the 4 quads
    total += __shfl_xor(total, 16, 64);
    total += __shfl_xor(total, 32, 64);

    if (lane == 0) wave_sum[wave] = total;
    __syncthreads();
    if (t == 0) {
        float s = 0.f;
#pragma unroll
        for (int w = 0; w < 8; ++w) s += wave_sum[w];
        out[bk] = s;
    }
}

extern "C" void kernel_launch(void* const* d_in, const int* in_sizes, int n_in,
                              void* d_out, int out_size, void* d_ws, size_t ws_size,
                              hipStream_t stream) {
    const float* context = (const float*)d_in[0];
    float* out = (float*)d_out;
    som_kernel<<<dim3(1024), dim3(512), 0, stream>>>(context, out);
}

// Round 3
// 987.256 us; speedup vs baseline: 1.0131x; 1.0051x over previous
//
#include <hip/hip_runtime.h>

// Problem: B=16, K=64, L=M=128, D=768, fp32 in, fp32 out (B*K=1024 scalars).
// out[bk] = sum_l max_m <ctx[bk,l,:], ent[bk,m,:]>
//
// One workgroup per bk; 1024 blocks of 512 threads (8 waves).
// D staged in 12 chunks of 64 (fp32 -> bf16), DOUBLE-BUFFERED in LDS.
//
// R2 change (resubmitted after infra failure): per-block CHUNK-ORDER STAGGER.
// The chunked read pattern is 256 B segments at 3072 B stride; in 256 B
// granules addr/256 = row*12 + c, and gcd(12, 2^k) = 4, so a fixed chunk c
// touches only channels == c (mod 4) -- 1/4 of HBM channels. All blocks in
// lockstep at the same c => measured 1.65 TB/s ~= 6.3/4. Staggering c by
// bk spreads concurrent blocks across all residues mod 4 => all channels
// busy. Chunk order is commutative (fp32 accumulation over D).

typedef __attribute__((ext_vector_type(8))) __bf16 bf16x8;
typedef __attribute__((ext_vector_type(4))) __bf16 bf16x4;
typedef __attribute__((ext_vector_type(4))) float f32x4;

#define L_DIM 128
#define D_DIM 768
#define DC    64          // D-chunk
#define NCHUNK (D_DIM / DC)
#define LDP   72          // padded LDS row (bf16 elems): 144 B rows, 16B-aligned frags

__global__ __launch_bounds__(512, 4)
void som_kernel(const float* __restrict__ context, float* __restrict__ out) {
    const int bk   = blockIdx.x;
    const int t    = threadIdx.x;
    const int lane = t & 63;
    const int wave = t >> 6;            // 0..7, owns rows [wave*16, wave*16+16)
    const int quad = (lane >> 4) & 3;   // 0..3
    const int l15  = lane & 15;

    const float* ctx_g = context + (size_t)bk * (2 * L_DIM * D_DIM);
    const float* ent_g = ctx_g + (size_t)(L_DIM * D_DIM);

    __shared__ __bf16 ctx_s[2][L_DIM * LDP];
    __shared__ __bf16 ent_s[2][L_DIM * LDP];
    __shared__ float wave_sum[8];

    // ---- staging geometry: 2048 float4 per array per chunk, 512 threads x 4 ----
    const int row0 = t >> 4;            // 0..31
    const int c4   = t & 15;
    const float* gc = ctx_g + row0 * D_DIM + c4 * 4;
    const float* ge = ent_g + row0 * D_DIM + c4 * 4;
    const int lds0 = row0 * LDP + c4 * 4;

    // per-block chunk-order stagger (channel decorrelation)
    const int c0 = bk % NCHUNK;

    f32x4 acc[8];
    const f32x4 zero = {0.f, 0.f, 0.f, 0.f};
#pragma unroll
    for (int ct = 0; ct < 8; ++ct) acc[ct] = zero;

    float4 pc[4], pe[4];

    // ---- prologue: stage chunk c0 into buffer 0 ----
    {
        const int base = c0 * DC;
#pragma unroll
        for (int i = 0; i < 4; ++i) {
            pc[i] = *(const float4*)(gc + i * 32 * D_DIM + base);
            pe[i] = *(const float4*)(ge + i * 32 * D_DIM + base);
        }
#pragma unroll
        for (int i = 0; i < 4; ++i) {
            bf16x4 qc = {(__bf16)pc[i].x, (__bf16)pc[i].y, (__bf16)pc[i].z, (__bf16)pc[i].w};
            bf16x4 qe = {(__bf16)pe[i].x, (__bf16)pe[i].y, (__bf16)pe[i].z, (__bf16)pe[i].w};
            *(bf16x4*)&ctx_s[0][lds0 + i * 32 * LDP] = qc;
            *(bf16x4*)&ent_s[0][lds0 + i * 32 * LDP] = qe;
        }
    }
    __syncthreads();

    // ---- main loop: one barrier per phase, loads always in flight ----
    for (int j = 0; j < NCHUNK; ++j) {
        const int cur = j & 1;

        // 1) issue ALL next-phase loads (8 KB/wave in flight across MFMA)
        if (j < NCHUNK - 1) {
            int cn = c0 + j + 1; if (cn >= NCHUNK) cn -= NCHUNK;
            const int base = cn * DC;
#pragma unroll
            for (int i = 0; i < 4; ++i) {
                pc[i] = *(const float4*)(gc + i * 32 * D_DIM + base);
                pe[i] = *(const float4*)(ge + i * 32 * D_DIM + base);
            }
        }

        // 2) MFMA on current buffer: wave's 16 rows x all 128 cols
        {
            const __bf16* cs = ctx_s[cur];
            const __bf16* es = ent_s[cur];
#pragma unroll
            for (int ks = 0; ks < 2; ++ks) {
                // A frag: A[m = l15][k = quad*8 + jj]
                const bf16x8 a = *(const bf16x8*)&cs[(wave * 16 + l15) * LDP + ks * 32 + quad * 8];
#pragma unroll
                for (int ct = 0; ct < 8; ++ct) {
                    // B frag: B[n = l15][k = quad*8 + jj]  (C = A * B^T: same layout as A)
                    const bf16x8 b = *(const bf16x8*)&es[(ct * 16 + l15) * LDP + ks * 32 + quad * 8];
                    acc[ct] = __builtin_amdgcn_mfma_f32_16x16x32_bf16(a, b, acc[ct], 0, 0, 0);
                }
            }
        }

        // 3) convert + write next chunk into the idle buffer
        if (j < NCHUNK - 1) {
            const int nxt = cur ^ 1;
#pragma unroll
            for (int i = 0; i < 4; ++i) {
                bf16x4 qc = {(__bf16)pc[i].x, (__bf16)pc[i].y, (__bf16)pc[i].z, (__bf16)pc[i].w};
                bf16x4 qe = {(__bf16)pe[i].x, (__bf16)pe[i].y, (__bf16)pe[i].z, (__bf16)pe[i].w};
                *(bf16x4*)&ctx_s[nxt][lds0 + i * 32 * LDP] = qc;
                *(bf16x4*)&ent_s[nxt][lds0 + i * 32 * LDP] = qe;
            }
        }
        __syncthreads();
    }

    // ---- epilogue: row-max over 128 cols, then sum of maxes ----
    // C/D layout: col = ct*16 + l15, row = wave*16 + quad*4 + reg.
    float total = 0.f;
#pragma unroll
    for (int reg = 0; reg < 4; ++reg) {
        float m = acc[0][reg];
#pragma unroll
        for (int ct = 1; ct < 8; ++ct) m = fmaxf(m, acc[ct][reg]);
        // max across the 16 lanes of this quad (cols of each 16-wide tile)
        m = fmaxf(m, __shfl_xor(m, 1, 64));
        m = fmaxf(m, __shfl_xor(m, 2, 64));
        m = fmaxf(m, __shfl_xor(m, 4, 64));
        m = fmaxf(m, __shfl_xor(m, 8, 64));
        total += m;   // every lane of the quad holds this row's max
    }
    // per-lane total = sum of this quad's 4 rows; combine the 4 quads
    total += __shfl_xor(total, 16, 64);
    total += __shfl_xor(total, 32, 64);

    if (lane == 0) wave_sum[wave] = total;
    __syncthreads();
    if (t == 0) {
        float s = 0.f;
#pragma unroll
        for (int w = 0; w < 8; ++w) s += wave_sum[w];
        out[bk] = s;
    }
}

extern "C" void kernel_launch(void* const* d_in, const int* in_sizes, int n_in,
                              void* d_out, int out_size, void* d_ws, size_t ws_size,
                              hipStream_t stream) {
    const float* context = (const float*)d_in[0];
    float* out = (float*)d_out;
    som_kernel<<<dim3(1024), dim3(512), 0, stream>>>(context, out);
}